// Round 5
// baseline (528.260 us; speedup 1.0000x reference)
//
#include <hip/hip_runtime.h>
#include <math.h>

constexpr int NN  = 100000;   // nodes
constexpr int NE  = 1600000;  // edges
constexpr int DIM = 128;
constexpr int NB  = (NN + 1 + 1023) / 1024;  // 98 scan blocks
constexpr int NBUCK = (NN + 255) / 256;      // 391 dst-buckets

typedef unsigned short ushort;
typedef unsigned int uint;
typedef __attribute__((ext_vector_type(8))) short bf16x8;
typedef __attribute__((ext_vector_type(4))) float f32x4;

// ---- workspace layout (bytes) ----
constexpr size_t OFF_FLAG   = 0;
constexpr size_t OFF_BSUM   = 512;
constexpr size_t OFF_ROWPTR = 1536;                      // int[NN+1]
constexpr size_t OFF_GCUR   = OFF_ROWPTR + 400128;       // int[NBUCK]
constexpr size_t OFF_COL    = OFF_GCUR   + 2048;         // int[NE]
constexpr size_t OFF_TMP    = OFF_COL    + 6400000;      // uint[NE] packed
constexpr size_t OFF_WT     = OFF_TMP    + 6400000;      // 4 x 128x128 bf16
constexpr size_t OFF_XB     = OFF_WT     + 131072;       // bf16[NN*128]
constexpr size_t OFF_HB     = OFF_XB     + 25600000;     // bf16[NN*128]
// total ≈ 64.9 MB

__device__ __forceinline__ int eidx(const void* p, int is64, long long i) {
  return is64 ? (int)((const long long*)p)[i] : ((const int*)p)[i];
}

__device__ __forceinline__ ushort f2b(float f) {  // fp32 -> bf16 RNE
  uint u = __float_as_uint(f);
  return (ushort)((u + 0x7FFFu + ((u >> 16) & 1u)) >> 16);
}
__device__ __forceinline__ float blo(uint u) { return __uint_as_float(u << 16); }
__device__ __forceinline__ float bhi(uint u) { return __uint_as_float(u & 0xFFFF0000u); }

__global__ void k_detect(const uint* e, int* flag) {
  uint v = 0;
  for (int i = threadIdx.x; i < 8192; i += blockDim.x) v |= e[2 * i + 1];
  if (v) atomicOr(flag, 1);
}

__global__ void k_hist(const void* e, const int* flag, int* rowptr) {
  int is64 = (*flag == 0);
  int i = blockIdx.x * blockDim.x + threadIdx.x;
  if (i < NE) {
    int dst = eidx(e, is64, (long long)NE + i);
    atomicAdd(&rowptr[dst + 1], 1);
  }
}

// hierarchical scan
__global__ __launch_bounds__(1024) void k_scan_a(int* rowptr, int* bsum) {
  int gid = blockIdx.x * 1024 + threadIdx.x;
  int lane = threadIdx.x & 63;
  int wid = threadIdx.x >> 6;
  int s = (gid < NN + 1) ? rowptr[gid] : 0;
#pragma unroll
  for (int off = 1; off < 64; off <<= 1) {
    int t = __shfl_up(s, off, 64);
    if (lane >= off) s += t;
  }
  __shared__ int wsum[16];
  if (lane == 63) wsum[wid] = s;
  __syncthreads();
  if (wid == 0) {
    int ws = (lane < 16) ? wsum[lane] : 0;
#pragma unroll
    for (int off = 1; off < 16; off <<= 1) {
      int t = __shfl_up(ws, off, 64);
      if (lane >= off) ws += t;
    }
    if (lane < 16) wsum[lane] = ws;
  }
  __syncthreads();
  if (wid > 0) s += wsum[wid - 1];
  if (gid < NN + 1) rowptr[gid] = s;
  if (threadIdx.x == 1023) bsum[blockIdx.x] = s;
}

__global__ void k_scan_b(int* bsum) {
  __shared__ int sh[128];
  int t = threadIdx.x;
  sh[t] = (t < NB) ? bsum[t] : 0;
  __syncthreads();
  for (int off = 1; off < 128; off <<= 1) {
    int v = (t >= off) ? sh[t - off] : 0;
    __syncthreads();
    sh[t] += v;
    __syncthreads();
  }
  if (t < NB) bsum[t] = (t > 0) ? sh[t - 1] : 0;
}

__global__ __launch_bounds__(1024) void k_scan_c(int* rowptr, const int* bsum) {
  int gid = blockIdx.x * 1024 + threadIdx.x;
  if (gid < NN + 1) rowptr[gid] += bsum[blockIdx.x];
}

// seed per-bucket write cursors (tmp shares segment layout with col)
__global__ void k_seed(const int* __restrict__ rowptr, int* __restrict__ gcur) {
  int b = blockIdx.x * blockDim.x + threadIdx.x;
  if (b < NBUCK) gcur[b] = rowptr[min(b << 8, NN)];
}

// LDS multisplit: group edges by dst-bucket into tmp with full-line flushes.
// packed entry = (src << 8) | (dst & 255)
__global__ __launch_bounds__(256) void k_bin(const void* e, const int* flag,
                                             int* gcur, uint* tmp) {
  __shared__ uint buf[NBUCK * 32];
  __shared__ int cnt[NBUCK];
  int is64 = (*flag == 0);
  for (int b = threadIdx.x; b < NBUCK; b += 256) cnt[b] = 0;
  __syncthreads();

  for (int base = blockIdx.x * 256; base < NE; base += gridDim.x * 256) {
    int i = base + threadIdx.x;
    if (i < NE) {
      int src = eidx(e, is64, i);
      int dst = eidx(e, is64, (long long)NE + i);
      int b = dst >> 8;
      uint pack = ((uint)src << 8) | (uint)(dst & 255);
      int c = atomicAdd(&cnt[b], 1);
      if (c < 32) {
        buf[b * 32 + c] = pack;
      } else {  // overflow (pathological skew) - direct fragmented store
        int p = atomicAdd(&gcur[b], 1);
        tmp[p] = pack;
      }
    }
    __syncthreads();
    // flush full 64B lines, one thread per bucket
    for (int b = threadIdx.x; b < NBUCK; b += 256) {
      int c = min(cnt[b], 32);
      if (c >= 16) {
        int gpos = atomicAdd(&gcur[b], 16);
        uint* s = &buf[b * 32];
#pragma unroll
        for (int q = 0; q < 4; q++) {
          uint4 v = {s[q * 4 + 0], s[q * 4 + 1], s[q * 4 + 2], s[q * 4 + 3]};
          *(uint4*)(tmp + gpos + q * 4) = v;
        }
        int rem = c - 16;
        for (int q = 0; q < rem; q++) s[q] = s[16 + q];
        cnt[b] = rem;
      } else {
        cnt[b] = c;
      }
    }
    __syncthreads();
  }
  // final residual flush
  for (int b = threadIdx.x; b < NBUCK; b += 256) {
    int c = cnt[b];
    if (c > 0) {
      int gpos = atomicAdd(&gcur[b], c);
      for (int q = 0; q < c; q++) tmp[gpos + q] = buf[b * 32 + q];
    }
  }
}

// one workgroup per bucket: order tmp segment into final CSR col
__global__ __launch_bounds__(256) void k_reorder(const int* __restrict__ rowptr,
                                                 const uint* __restrict__ tmp,
                                                 int* __restrict__ col) {
  __shared__ int lcur[256];
  int b = blockIdx.x;
  int nodeBase = b << 8;
  int segBeg = rowptr[min(nodeBase, NN)];
  int segEnd = rowptr[min(nodeBase + 256, NN)];
  int node = nodeBase + threadIdx.x;
  lcur[threadIdx.x] = rowptr[min(node, NN)];
  __syncthreads();
  for (int j = segBeg + threadIdx.x; j < segEnd; j += 256) {
    uint p = tmp[j];
    int dlocal = p & 255;
    int src = p >> 8;
    int pos = atomicAdd(&lcur[dlocal], 1);
    col[pos] = src;
  }
}

// x fp32 -> bf16
__global__ void k_cvt(const float* __restrict__ x, ushort* __restrict__ xb) {
  int i = blockIdx.x * blockDim.x + threadIdx.x;
  if (i * 4 < NN * DIM) {
    float4 v = ((const float4*)x)[i];
    ushort4 o = {f2b(v.x), f2b(v.y), f2b(v.z), f2b(v.w)};
    ((ushort4*)xb)[i] = o;
  }
}

// 4 weight matrices [k][n] fp32 -> transposed [n][k] bf16
__global__ void k_cvtw(const float* __restrict__ W1l, const float* __restrict__ W1r,
                       const float* __restrict__ W2l, const float* __restrict__ W2r,
                       ushort* __restrict__ WT) {
  int id = blockIdx.x * 256 + threadIdx.x;
  int m = id >> 14, idx = id & 16383;
  int k = idx >> 7, n = idx & 127;
  const float* W = (m == 0) ? W1l : (m == 1) ? W1r : (m == 2) ? W2l : W2r;
  WT[m * 16384 + n * 128 + k] = f2b(W[k * 128 + n]);
}

// Fused SAGE layer: per 4-wave block of 64 nodes, each wave
//  stage 1: mean-aggregates its 16 nodes' neighbor rows into a swizzled LDS
//           bf16 tile (wave-private -> no barrier),
//  stage 2: MFMA C = act(agg@Wl + feat@Wr + bias).
// MODE 0: relu -> bf16 out [NN][128]. MODE 1: relu -> heads -> d_out.
template <int MODE>
__global__ __launch_bounds__(256) void k_fused(
    const ushort* __restrict__ feat,
    const int* __restrict__ rowptr, const int* __restrict__ col,
    const ushort* __restrict__ B1t, const ushort* __restrict__ B2t,
    const float* __restrict__ bias, void* __restrict__ outp,
    const float* __restrict__ Wp, const float* __restrict__ bp,
    const float* __restrict__ Wd, const float* __restrict__ bd) {
  __shared__ ushort Ms[64 * 128];  // 16KB, rows XOR-swizzled in 16B slots
  int wid = threadIdx.x >> 6, lane = threadIdx.x & 63;
  int row0 = blockIdx.x * 64 + wid * 16;
  const uint* F = (const uint*)feat;
  uint* MsU = (uint*)Ms;
  int slot = lane >> 2;  // 16B slot 0..15
  int sub = lane & 3;

  // ---- stage 1: aggregate ----
  for (int i = 0; i < 16; i++) {
    int v = row0 + i;
    float ax = 0.f, ay = 0.f;
    if (v < NN) {
      int beg = rowptr[v], end = rowptr[v + 1];
      int j = beg;
      for (; j + 3 < end; j += 4) {
        int c0 = col[j], c1 = col[j + 1], c2 = col[j + 2], c3 = col[j + 3];
        uint u0 = F[(size_t)c0 * 64 + lane];
        uint u1 = F[(size_t)c1 * 64 + lane];
        uint u2 = F[(size_t)c2 * 64 + lane];
        uint u3 = F[(size_t)c3 * 64 + lane];
        ax += blo(u0) + blo(u1) + blo(u2) + blo(u3);
        ay += bhi(u0) + bhi(u1) + bhi(u2) + bhi(u3);
      }
      for (; j < end; j++) {
        uint u = F[(size_t)col[j] * 64 + lane];
        ax += blo(u);
        ay += bhi(u);
      }
      float inv = 1.0f / (float)max(end - beg, 1);
      ax *= inv;
      ay *= inv;
    }
    int lr = wid * 16 + i;
    int sw = slot ^ (lr & 7);
    MsU[lr * 64 + sw * 4 + sub] = (uint)f2b(ax) | ((uint)f2b(ay) << 16);
  }
  // no __syncthreads: each wave reads only rows it wrote

  // ---- stage 2: MFMA ----
  int r = lane & 15, kg = lane >> 4;
  f32x4 acc[8];
#pragma unroll
  for (int f = 0; f < 8; f++) acc[f] = (f32x4){0.f, 0.f, 0.f, 0.f};

  int lr = wid * 16 + r;
  int arow = row0 + r;
  bool aok = arow < NN;
  const ushort* Ar2 = feat + (size_t)arow * DIM + kg * 8;

#pragma unroll
  for (int half = 0; half < 2; half++) {
    const ushort* Bt = half ? B2t : B1t;
#pragma unroll
    for (int ks = 0; ks < 4; ks++) {
      bf16x8 a;
      if (half == 0) {
        int s0 = kg + ks * 4;  // 16B slot of cols [kg*8+ks*32 .. +7]
        a = *(const bf16x8*)&Ms[lr * 128 + ((s0 ^ (lr & 7)) << 3)];
      } else {
        a = aok ? *(const bf16x8*)(Ar2 + ks * 32)
                : (bf16x8){0, 0, 0, 0, 0, 0, 0, 0};
      }
      const ushort* bp0 = Bt + r * 128 + kg * 8 + ks * 32;
#pragma unroll
      for (int f = 0; f < 8; f++) {
        bf16x8 b = *(const bf16x8*)(bp0 + f * 16 * 128);
        acc[f] = __builtin_amdgcn_mfma_f32_16x16x32_bf16(a, b, acc[f], 0, 0, 0);
      }
    }
  }

  // D layout: lane,reg rr -> row = row0 + kg*4 + rr, col = f*16 + r
  if (MODE == 0) {
    ushort* O = (ushort*)outp;
#pragma unroll
    for (int rr = 0; rr < 4; rr++) {
      int orow = row0 + kg * 4 + rr;
      if (orow < NN) {
#pragma unroll
        for (int f = 0; f < 8; f++) {
          int n = f * 16 + r;
          float h = fmaxf(acc[f][rr] + bias[n], 0.f);
          O[(size_t)orow * DIM + n] = f2b(h);
        }
      }
    }
  } else {
    float* O = (float*)outp;
    float bpv = bp[0], bdv = bd[0];
#pragma unroll
    for (int rr = 0; rr < 4; rr++) {
      float p = 0.f, dv = 0.f;
#pragma unroll
      for (int f = 0; f < 8; f++) {
        int n = f * 16 + r;
        float h = fmaxf(acc[f][rr] + bias[n], 0.f);
        p += h * Wp[n];
        dv += h * Wd[n];
      }
#pragma unroll
      for (int m = 1; m < 16; m <<= 1) {
        p += __shfl_xor(p, m, 64);
        dv += __shfl_xor(dv, m, 64);
      }
      int orow = row0 + kg * 4 + rr;
      if (r == 0 && orow < NN) {
        float preds = p + bpv;
        float diffs = 1.f / (1.f + expf(-(dv + bdv)));
        O[orow] = preds - diffs;
        O[NN + orow] = preds + diffs;
      }
    }
  }
}

extern "C" void kernel_launch(void* const* d_in, const int* in_sizes, int n_in,
                              void* d_out, int out_size, void* d_ws, size_t ws_size,
                              hipStream_t stream) {
  const float* x   = (const float*)d_in[0];
  const void*  ei  = d_in[1];
  const float* W1l = (const float*)d_in[2];
  const float* b1  = (const float*)d_in[3];
  const float* W1r = (const float*)d_in[4];
  const float* W2l = (const float*)d_in[5];
  const float* b2  = (const float*)d_in[6];
  const float* W2r = (const float*)d_in[7];
  const float* Wp  = (const float*)d_in[8];
  const float* bp  = (const float*)d_in[9];
  const float* Wd  = (const float*)d_in[10];
  const float* bd  = (const float*)d_in[11];

  char* ws = (char*)d_ws;
  int* flag   = (int*)(ws + OFF_FLAG);
  int* bsum   = (int*)(ws + OFF_BSUM);
  int* rowptr = (int*)(ws + OFF_ROWPTR);
  int* gcur   = (int*)(ws + OFF_GCUR);
  int* col    = (int*)(ws + OFF_COL);
  uint* tmp   = (uint*)(ws + OFF_TMP);
  ushort* WT  = (ushort*)(ws + OFF_WT);
  ushort* Xb  = (ushort*)(ws + OFF_XB);
  ushort* Hb  = (ushort*)(ws + OFF_HB);

  hipMemsetAsync(flag, 0, sizeof(int), stream);
  hipMemsetAsync(rowptr, 0, (NN + 1) * sizeof(int), stream);
  k_detect<<<1, 256, 0, stream>>>((const uint*)ei, flag);
  k_hist<<<(NE + 255) / 256, 256, 0, stream>>>(ei, flag, rowptr);
  k_scan_a<<<NB, 1024, 0, stream>>>(rowptr, bsum);
  k_scan_b<<<1, 128, 0, stream>>>(bsum);
  k_scan_c<<<NB, 1024, 0, stream>>>(rowptr, bsum);
  k_seed<<<2, 256, 0, stream>>>(rowptr, gcur);
  k_bin<<<128, 256, 0, stream>>>(ei, flag, gcur, tmp);
  k_reorder<<<NBUCK, 256, 0, stream>>>(rowptr, tmp, col);

  k_cvt<<<(NN * DIM / 4 + 255) / 256, 256, 0, stream>>>(x, Xb);
  k_cvtw<<<256, 256, 0, stream>>>(W1l, W1r, W2l, W2r, WT);

  // layer 1 (agg + GEMM fused)
  k_fused<0><<<(NN + 63) / 64, 256, 0, stream>>>(Xb, rowptr, col, WT, WT + 16384,
                                                 b1, Hb, nullptr, nullptr, nullptr,
                                                 nullptr);
  // layer 2 + heads
  k_fused<1><<<(NN + 63) / 64, 256, 0, stream>>>(Hb, rowptr, col, WT + 32768,
                                                 WT + 49152, b2, d_out, Wp, bp, Wd,
                                                 bd);
}